// Round 1
// baseline (214.594 us; speedup 1.0000x reference)
//
#include <hip/hip_runtime.h>
#include <hip/hip_bf16.h>

// Problem constants
#define BATCH 2048
// pooled: [45][14][14] = 8820 floats per image
// tree_w: [16][15][3][7][7][2][2] (f,m,g,i,j,ki,kj), strides f:8820 m:588 g:196 i:28 j:4 ki:2 kj:1
// t:      [b][336], idx = f*21 + g*7 + i
// out:    [b][10]

__device__ __forceinline__ float sigmoidf(float v) {
    return 1.0f / (1.0f + __expf(-v));
}

// ---------------- k1: grouped conv 5x5 + bias + sigmoid + maxpool2 ----------------
// one image per block, 256 threads
__global__ __launch_bounds__(256) void k1_conv_pool(
    const float* __restrict__ x,       // [B][3][32][32]
    const float* __restrict__ conv_w,  // [45][25]
    const float* __restrict__ conv_b,  // [45]
    float* __restrict__ pooled,        // [chunk][8820]
    int b0)
{
    const int img = b0 + blockIdx.x;
    __shared__ float xs[3 * 32 * 33];   // padded row stride 33 (bank-conflict fix)
    __shared__ float ws[45 * 25];
    __shared__ float bs[45];
    __shared__ float ps[45 * 196];      // pooled staging, 34.5 KB

    const int tid = threadIdx.x;

    // load x image (12 KB) with float4 global loads, scalar padded LDS stores
    const float4* xg = (const float4*)(x + (size_t)img * 3072);
    for (int idx = tid; idx < 768; idx += 256) {
        float4 v = xg[idx];
        int flat = idx * 4;
        int gch = flat >> 10;           // channel 0..2
        int rc = flat & 1023;
        int row = rc >> 5;
        int col = rc & 31;
        float* dst = xs + (gch * 32 + row) * 33 + col;
        dst[0] = v.x; dst[1] = v.y; dst[2] = v.z; dst[3] = v.w;
    }
    for (int idx = tid; idx < 1125; idx += 256) ws[idx] = conv_w[idx];
    if (tid < 45) bs[tid] = conv_b[tid];
    __syncthreads();

    // tasks: (c 0..44, ph 0..13, half 0..1) -> 1260 tasks
    for (int task = tid; task < 1260; task += 256) {
        const int half = task & 1;
        const int t2 = task >> 1;
        const int ph = t2 % 14;
        const int c  = t2 / 14;
        const int g  = c / 15;

        const float* xbase = xs + (g * 32 + 2 * ph) * 33 + half * 14;
        const float* wc = ws + c * 25;

        float acc0[14], acc1[14];
        #pragma unroll
        for (int j = 0; j < 14; j++) { acc0[j] = 0.f; acc1[j] = 0.f; }

        #pragma unroll
        for (int r = 0; r < 6; r++) {
            float xr[18];
            #pragma unroll
            for (int j2 = 0; j2 < 18; j2++) xr[j2] = xbase[r * 33 + j2];
            if (r < 5) {
                #pragma unroll
                for (int kw = 0; kw < 5; kw++) {
                    float wv = wc[r * 5 + kw];
                    #pragma unroll
                    for (int j = 0; j < 14; j++) acc0[j] += xr[j + kw] * wv;
                }
            }
            if (r >= 1) {
                #pragma unroll
                for (int kw = 0; kw < 5; kw++) {
                    float wv = wc[(r - 1) * 5 + kw];
                    #pragma unroll
                    for (int j = 0; j < 14; j++) acc1[j] += xr[j + kw] * wv;
                }
            }
        }
        // maxpool pre-activations, then single bias+sigmoid
        const float bias = bs[c];
        float* prow = ps + c * 196 + ph * 14 + half * 7;
        #pragma unroll
        for (int jj = 0; jj < 7; jj++) {
            float m = fmaxf(fmaxf(acc0[2 * jj], acc0[2 * jj + 1]),
                            fmaxf(acc1[2 * jj], acc1[2 * jj + 1]));
            prow[jj] = sigmoidf(m + bias);
        }
    }
    __syncthreads();

    // coalesced write-out
    float* pg = pooled + (size_t)blockIdx.x * 8820;
    for (int idx = tid; idx < 8820; idx += 256) pg[idx] = ps[idx];
}

// ---------------- k2: tree einsum + bias + sigmoid ----------------
// grid: (nimg/16, 21); block 256 = 16 images x 16 filters
__global__ __launch_bounds__(256) void k2_tree(
    const float* __restrict__ pooled,   // [chunk][8820]
    const float* __restrict__ tree_w,   // [16][15][3][7][7][2][2]
    const float* __restrict__ tree_b,   // [16][3][7]
    float* __restrict__ t_out,          // [chunk][336]
    int nimg)
{
    const int bt = blockIdx.x;
    const int gi = blockIdx.y;          // 0..20
    const int g = gi / 7;
    const int i = gi % 7;

    __shared__ float Wl[420 * 17];      // Wl[k*17 + f], stride-17 pad

    const int tid = threadIdx.x;
    // load weight slice: idx = f*420 + k ; k = m*28 + rem
    for (int idx = tid; idx < 6720; idx += 256) {
        int f = idx / 420;
        int k = idx - f * 420;
        int m = k / 28;
        int rem = k - m * 28;
        Wl[k * 17 + f] = tree_w[f * 8820 + m * 588 + g * 196 + i * 28 + rem];
    }
    __syncthreads();

    const int f = tid & 15;
    const int b = tid >> 4;             // 0..15
    const float* pb = pooled + (size_t)(bt * 16 + b) * 8820;

    float acc_a = 0.f, acc_b = 0.f;
    for (int m = 0; m < 15; m++) {
        const float* pc = pb + (g * 15 + m) * 196 + (2 * i) * 14;
        const float* wm = Wl + m * 28 * 17;
        #pragma unroll
        for (int w = 0; w < 14; w++) {
            int j = w >> 1, kj = w & 1;
            // ki = 0
            acc_a += pc[w]      * wm[(j * 4 + kj) * 17 + f];
            // ki = 1
            acc_b += pc[14 + w] * wm[(j * 4 + 2 + kj) * 17 + f];
        }
    }
    float acc = acc_a + acc_b + tree_b[f * 21 + gi];
    t_out[(size_t)(bt * 16 + b) * 336 + f * 21 + gi] = sigmoidf(acc);
}

// ---------------- k3: fc 336 -> 10 ----------------
__global__ __launch_bounds__(256) void k3_fc(
    const float* __restrict__ t_in,     // [chunk][336]
    const float* __restrict__ fc_w,     // [10][336]
    const float* __restrict__ fc_b,     // [10]
    float* __restrict__ out,            // [chunk][10]
    int nimg)
{
    __shared__ float wl[10 * 336];
    const int tid = threadIdx.x;
    for (int idx = tid; idx < 3360; idx += 256) wl[idx] = fc_w[idx];
    __syncthreads();

    const int gidx = blockIdx.x * 256 + tid;
    if (gidx >= nimg * 10) return;
    const int b = gidx / 10;
    const int o = gidx - b * 10;
    const float* tb = t_in + (size_t)b * 336;
    const float* wo = wl + o * 336;
    float acc = fc_b[o];
    #pragma unroll 4
    for (int c = 0; c < 336; c++) acc += tb[c] * wo[c];
    out[(size_t)b * 10 + o] = acc;
}

extern "C" void kernel_launch(void* const* d_in, const int* in_sizes, int n_in,
                              void* d_out, int out_size, void* d_ws, size_t ws_size,
                              hipStream_t stream) {
    const float* x      = (const float*)d_in[0];
    const float* conv_w = (const float*)d_in[1];
    const float* conv_b = (const float*)d_in[2];
    const float* tree_w = (const float*)d_in[3];
    const float* tree_b = (const float*)d_in[4];
    const float* fc_w   = (const float*)d_in[5];
    const float* fc_b   = (const float*)d_in[6];
    float* out = (float*)d_out;

    // workspace layout per chunk: pooled[chunk*8820] + t[chunk*336]
    const size_t per_img_bytes = (8820 + 336) * sizeof(float);
    int chunk = (int)(ws_size / per_img_bytes);
    if (chunk > BATCH) chunk = BATCH;
    chunk &= ~15;                       // multiple of 16
    if (chunk < 16) chunk = 16;         // minimal fallback

    float* pooled = (float*)d_ws;
    float* t_ws   = (float*)d_ws + (size_t)chunk * 8820;

    for (int b0 = 0; b0 < BATCH; b0 += chunk) {
        int nimg = BATCH - b0;
        if (nimg > chunk) nimg = chunk;

        k1_conv_pool<<<nimg, 256, 0, stream>>>(x, conv_w, conv_b, pooled, b0);

        dim3 g2(nimg / 16, 21);
        k2_tree<<<g2, 256, 0, stream>>>(pooled, tree_w, tree_b, t_ws, nimg);

        int nthreads = nimg * 10;
        k3_fc<<<(nthreads + 255) / 256, 256, 0, stream>>>(t_ws, fc_w, fc_b,
                                                          out + (size_t)b0 * 10, nimg);
    }
}

// Round 2
// 204.544 us; speedup vs baseline: 1.0491x; 1.0491x over previous
//
#include <hip/hip_runtime.h>
#include <hip/hip_bf16.h>

// Problem constants
#define BATCH 2048
// ps (pooled, LDS): [45][14][14] = 8820 floats per image
// tree_w: [16][15][3][7][7][2][2] (f,m,g,i,j,ki,kj) strides f:8820 m:588 g:196 i:28 j:4 ki:2 kj:1
// t: [336] per image, idx = f*21 + g*7 + i ; out: [b][10]

__device__ __forceinline__ float sigmoidf(float v) {
    return 1.0f / (1.0f + __expf(-v));
}

// Fully fused: grouped conv 5x5 + bias + sigmoid + maxpool2 + tree einsum + sigmoid + fc.
// One image per block, 256 threads. pooled never touches HBM.
__global__ __launch_bounds__(256) void fused_all(
    const float* __restrict__ x,       // [B][3][32][32]
    const float* __restrict__ conv_w,  // [45][25]
    const float* __restrict__ conv_b,  // [45]
    const float* __restrict__ tree_w,  // [16][15][3][7][7][2][2]
    const float* __restrict__ tree_b,  // [16][3][7] flat 336
    const float* __restrict__ fc_w,    // [10][336]
    const float* __restrict__ fc_b,    // [10]
    float* __restrict__ out)           // [B][10]
{
    const int img = blockIdx.x;
    __shared__ float xs[3 * 32 * 33];   // padded row stride 33
    __shared__ float ws[45 * 25];
    __shared__ float bs[45];
    __shared__ float ps[45 * 196];      // pooled staging (LDS only)
    __shared__ float ts[336];           // tree output

    const int tid = threadIdx.x;

    // ---- stage x image (12 KB) ----
    const float4* xg = (const float4*)(x + (size_t)img * 3072);
    for (int idx = tid; idx < 768; idx += 256) {
        float4 v = xg[idx];
        int flat = idx * 4;
        int gch = flat >> 10;           // channel 0..2
        int rc = flat & 1023;
        int row = rc >> 5;
        int col = rc & 31;
        float* dst = xs + (gch * 32 + row) * 33 + col;
        dst[0] = v.x; dst[1] = v.y; dst[2] = v.z; dst[3] = v.w;
    }
    for (int idx = tid; idx < 1125; idx += 256) ws[idx] = conv_w[idx];
    if (tid < 45) bs[tid] = conv_b[tid];
    __syncthreads();

    // ---- conv + pool + sigmoid: tasks (c 0..44, ph 0..13, half 0..1) ----
    for (int task = tid; task < 1260; task += 256) {
        const int half = task & 1;
        const int t2 = task >> 1;
        const int ph = t2 % 14;
        const int c  = t2 / 14;
        const int g  = c / 15;

        const float* xbase = xs + (g * 32 + 2 * ph) * 33 + half * 14;
        const float* wc = ws + c * 25;

        float acc0[14], acc1[14];
        #pragma unroll
        for (int j = 0; j < 14; j++) { acc0[j] = 0.f; acc1[j] = 0.f; }

        #pragma unroll
        for (int r = 0; r < 6; r++) {
            float xr[18];
            #pragma unroll
            for (int j2 = 0; j2 < 18; j2++) xr[j2] = xbase[r * 33 + j2];
            if (r < 5) {
                #pragma unroll
                for (int kw = 0; kw < 5; kw++) {
                    float wv = wc[r * 5 + kw];
                    #pragma unroll
                    for (int j = 0; j < 14; j++) acc0[j] += xr[j + kw] * wv;
                }
            }
            if (r >= 1) {
                #pragma unroll
                for (int kw = 0; kw < 5; kw++) {
                    float wv = wc[(r - 1) * 5 + kw];
                    #pragma unroll
                    for (int j = 0; j < 14; j++) acc1[j] += xr[j + kw] * wv;
                }
            }
        }
        const float bias = bs[c];
        float* prow = ps + c * 196 + ph * 14 + half * 7;
        #pragma unroll
        for (int jj = 0; jj < 7; jj++) {
            float m = fmaxf(fmaxf(acc0[2 * jj], acc0[2 * jj + 1]),
                            fmaxf(acc1[2 * jj], acc1[2 * jj + 1]));
            prow[jj] = sigmoidf(m + bias);
        }
    }
    __syncthreads();

    // ---- tree einsum + bias + sigmoid: 336 outputs ----
    for (int o = tid; o < 336; o += 256) {
        const int f  = o / 21;
        const int gi = o - f * 21;
        const int g  = gi / 7;
        const int i  = gi - g * 7;

        float acc = 0.f;
        for (int m = 0; m < 15; m++) {
            const float4* wp = (const float4*)(tree_w + (size_t)f * 8820 + m * 588 + g * 196 + i * 28);
            const float4* pp = (const float4*)(ps + (g * 15 + m) * 196 + i * 28);
            float w28[28], p28[28];
            #pragma unroll
            for (int q = 0; q < 7; q++) {
                float4 wv = wp[q];
                w28[4 * q + 0] = wv.x; w28[4 * q + 1] = wv.y;
                w28[4 * q + 2] = wv.z; w28[4 * q + 3] = wv.w;
                float4 pv = pp[q];
                p28[4 * q + 0] = pv.x; p28[4 * q + 1] = pv.y;
                p28[4 * q + 2] = pv.z; p28[4 * q + 3] = pv.w;
            }
            // ps index: ki*14 + 2j + kj ; weight index: j*4 + ki*2 + kj
            #pragma unroll
            for (int j = 0; j < 7; j++) {
                #pragma unroll
                for (int ki = 0; ki < 2; ki++) {
                    #pragma unroll
                    for (int kj = 0; kj < 2; kj++) {
                        acc += p28[ki * 14 + 2 * j + kj] * w28[j * 4 + ki * 2 + kj];
                    }
                }
            }
        }
        ts[o] = sigmoidf(acc + tree_b[o]);
    }
    __syncthreads();

    // ---- fc 336 -> 10: wave-per-output, shuffle reduce ----
    const int wid  = tid >> 6;
    const int lane = tid & 63;
    for (int o = wid; o < 10; o += 4) {
        float partial = 0.f;
        for (int idx = lane; idx < 336; idx += 64)
            partial += ts[idx] * fc_w[o * 336 + idx];
        #pragma unroll
        for (int off = 32; off > 0; off >>= 1)
            partial += __shfl_down(partial, off);
        if (lane == 0)
            out[(size_t)img * 10 + o] = partial + fc_b[o];
    }
}

extern "C" void kernel_launch(void* const* d_in, const int* in_sizes, int n_in,
                              void* d_out, int out_size, void* d_ws, size_t ws_size,
                              hipStream_t stream) {
    const float* x      = (const float*)d_in[0];
    const float* conv_w = (const float*)d_in[1];
    const float* conv_b = (const float*)d_in[2];
    const float* tree_w = (const float*)d_in[3];
    const float* tree_b = (const float*)d_in[4];
    const float* fc_w   = (const float*)d_in[5];
    const float* fc_b   = (const float*)d_in[6];
    float* out = (float*)d_out;

    fused_all<<<BATCH, 256, 0, stream>>>(x, conv_w, conv_b, tree_w, tree_b,
                                         fc_w, fc_b, out);
}

// Round 3
// 167.596 us; speedup vs baseline: 1.2804x; 1.2205x over previous
//
#include <hip/hip_runtime.h>
#include <hip/hip_fp16.h>

#define BATCH 2048

__device__ __forceinline__ float sigmoidf(float v) {
    return 1.0f / (1.0f + __expf(-v));
}

// ---------------------------------------------------------------------------
// W2 layout (f16, in d_ws): [q=0..19][t=0..1007] of float4 (8 halves).
//   t = c0*336 + o ; o = f*21 + g*7 + i  (c0 = m-chunk 0..2, m = c0*5 + m_l)
//   q: m_l = q>>2, rem0 = (q&3)*8 ; element rem = rem0+u (valid < 28, else 0)
//   src = tree_w[f*8820 + m*588 + g*196 + i*28 + rem]   (rem = j*4 + ki*2 + kj)
// ---------------------------------------------------------------------------
__global__ __launch_bounds__(256) void k_prep(
    const float* __restrict__ tree_w,
    float4* __restrict__ W2)            // 20160 float4 = 315 KB
{
    int idx = blockIdx.x * 256 + threadIdx.x;   // one per (q,t)
    if (idx >= 20160) return;
    int q = idx / 1008;
    int t = idx - q * 1008;
    int c0 = t / 336;
    int o  = t - c0 * 336;
    int f  = o / 21;
    int gi = o - f * 21;
    int g  = gi / 7;
    int i  = gi - g * 7;
    int m  = c0 * 5 + (q >> 2);
    int rem0 = (q & 3) * 8;
    const float* src = tree_w + (size_t)f * 8820 + m * 588 + g * 196 + i * 28;
    union { float4 f4; __half h[8]; } u;
    #pragma unroll
    for (int uu = 0; uu < 8; uu++) {
        int rem = rem0 + uu;
        u.h[uu] = __float2half(rem < 28 ? src[rem] : 0.f);
    }
    W2[q * 1008 + t] = u.f4;
}

// ---------------------------------------------------------------------------
// Fully fused main kernel: conv5x5(grouped) + bias + sigmoid + maxpool2
//                          + tree einsum + sigmoid + fc.  One image per block.
// LDS plan (35,040 B -> 4 blocks/CU):
//   [0      .. 12672)  xs   float[3*32*33]      | after conv barrier:
//                                               |   partials float[1008] @0
//                                               |   ts       float[336]  @4096
//   [12672  .. 17172)  ws   float[1125]
//   [17172  .. 17352)  bs   float[45]
//   [17360  .. 35016)  ps   __half[8828]  (tree-order pooled + 8 zero pad)
// ---------------------------------------------------------------------------
#define XS_OFF   0
#define WS_OFF   12672
#define BS_OFF   17172
#define PS_OFF   17360
#define PART_OFF 0
#define TS_OFF   4096
#define SMEM_SZ  35040

__global__ __launch_bounds__(256, 4) void fused_all(
    const float* __restrict__ x,       // [B][3][32][32]
    const float* __restrict__ conv_w,  // [45][25]
    const float* __restrict__ conv_b,  // [45]
    const float4* __restrict__ W2,     // prepped f16 tree weights
    const float* __restrict__ tree_b,  // [336]
    const float* __restrict__ fc_w,    // [10][336]
    const float* __restrict__ fc_b,    // [10]
    float* __restrict__ out)           // [B][10]
{
    __shared__ __align__(16) char smem[SMEM_SZ];
    float*  xs = (float*)(smem + XS_OFF);
    float*  ws = (float*)(smem + WS_OFF);
    float*  bs = (float*)(smem + BS_OFF);
    __half* ps = (__half*)(smem + PS_OFF);
    float*  partials = (float*)(smem + PART_OFF);
    float*  ts = (float*)(smem + TS_OFF);

    const int img = blockIdx.x;
    const int tid = threadIdx.x;

    // ---- stage x image (12 KB), conv weights, bias; zero ps pad ----
    const float4* xg = (const float4*)(x + (size_t)img * 3072);
    for (int idx = tid; idx < 768; idx += 256) {
        float4 v = xg[idx];
        int flat = idx * 4;
        int gch = flat >> 10;
        int rc = flat & 1023;
        int row = rc >> 5;
        int col = rc & 31;
        float* dst = xs + (gch * 32 + row) * 33 + col;
        dst[0] = v.x; dst[1] = v.y; dst[2] = v.z; dst[3] = v.w;
    }
    for (int idx = tid; idx < 1125; idx += 256) ws[idx] = conv_w[idx];
    if (tid < 45) bs[tid] = conv_b[tid];
    if (tid < 8) ps[8820 + tid] = __float2half(0.f);   // pad for tail reads
    __syncthreads();

    // ---- conv + pool + sigmoid ----
    // task = c*28 + half*14 + ph  (ph in low bits -> conflict-free xs reads)
    for (int task = tid; task < 1260; task += 256) {
        const int c    = task / 28;
        const int r28  = task - c * 28;
        const int half = r28 / 14;
        const int ph   = r28 - half * 14;
        const int g    = c / 15;

        const float* xbase = xs + (g * 32 + 2 * ph) * 33 + half * 14;
        const float* wc = ws + c * 25;

        float acc0[14], acc1[14];
        #pragma unroll
        for (int j = 0; j < 14; j++) { acc0[j] = 0.f; acc1[j] = 0.f; }

        #pragma unroll
        for (int r = 0; r < 6; r++) {
            float xr[18];
            #pragma unroll
            for (int j2 = 0; j2 < 18; j2++) xr[j2] = xbase[r * 33 + j2];
            if (r < 5) {
                #pragma unroll
                for (int kw = 0; kw < 5; kw++) {
                    float wv = wc[r * 5 + kw];
                    #pragma unroll
                    for (int j = 0; j < 14; j++) acc0[j] += xr[j + kw] * wv;
                }
            }
            if (r >= 1) {
                #pragma unroll
                for (int kw = 0; kw < 5; kw++) {
                    float wv = wc[(r - 1) * 5 + kw];
                    #pragma unroll
                    for (int j = 0; j < 14; j++) acc1[j] += xr[j + kw] * wv;
                }
            }
        }
        // pool pre-activation; store f16 in tree order: c*196 + i*28 + j*4 + ki*2 + kj
        const float bias = bs[c];
        const int i_ = ph >> 1, ki = ph & 1;
        __half* pbase = ps + c * 196 + i_ * 28 + ki * 2;
        #pragma unroll
        for (int jj = 0; jj < 7; jj++) {
            const int pc = half * 7 + jj;
            const int j = pc >> 1, kj = pc & 1;
            float m = fmaxf(fmaxf(acc0[2 * jj], acc0[2 * jj + 1]),
                            fmaxf(acc1[2 * jj], acc1[2 * jj + 1]));
            pbase[j * 4 + kj] = __float2half(sigmoidf(m + bias));
        }
    }
    __syncthreads();

    // ---- tree einsum, 1008 balanced tasks (3 m-chunks per output) ----
    for (int t = tid; t < 1008; t += 256) {
        const int c0 = t / 336;
        const int o  = t - c0 * 336;
        const int f  = o / 21;
        const int gi = o - f * 21;
        const int g  = gi / 7;
        const int i  = gi - g * 7;

        const __half* prow = ps + (g * 15 + c0 * 5) * 196 + i * 28;
        float acc = 0.f;
        #pragma unroll
        for (int q = 0; q < 20; q++) {
            union { float4 f4; __half2 h2[4]; } wu;
            wu.f4 = W2[q * 1008 + t];
            const int m_l = q >> 2;
            const int rem0 = (q & 3) * 8;
            const __half2* pp = (const __half2*)(prow + m_l * 196 + rem0);
            #pragma unroll
            for (int v = 0; v < 4; v++) {
                float2 pf = __half22float2(pp[v]);
                float2 wf = __half22float2(wu.h2[v]);
                acc = fmaf(pf.x, wf.x, acc);
                acc = fmaf(pf.y, wf.y, acc);
            }
        }
        partials[t] = acc;
    }
    __syncthreads();

    // ---- finalize tree: sum 3 partials + bias, sigmoid ----
    for (int o = tid; o < 336; o += 256) {
        float v = partials[o] + partials[o + 336] + partials[o + 672] + tree_b[o];
        ts[o] = sigmoidf(v);
    }
    __syncthreads();

    // ---- fc 336 -> 10: wave per output, shuffle reduce ----
    const int wid  = tid >> 6;
    const int lane = tid & 63;
    for (int o = wid; o < 10; o += 4) {
        float partial = 0.f;
        for (int idx = lane; idx < 336; idx += 64)
            partial += ts[idx] * fc_w[o * 336 + idx];
        #pragma unroll
        for (int off = 32; off > 0; off >>= 1)
            partial += __shfl_down(partial, off);
        if (lane == 0)
            out[(size_t)img * 10 + o] = partial + fc_b[o];
    }
}

extern "C" void kernel_launch(void* const* d_in, const int* in_sizes, int n_in,
                              void* d_out, int out_size, void* d_ws, size_t ws_size,
                              hipStream_t stream) {
    const float* x      = (const float*)d_in[0];
    const float* conv_w = (const float*)d_in[1];
    const float* conv_b = (const float*)d_in[2];
    const float* tree_w = (const float*)d_in[3];
    const float* tree_b = (const float*)d_in[4];
    const float* fc_w   = (const float*)d_in[5];
    const float* fc_b   = (const float*)d_in[6];
    float* out = (float*)d_out;

    float4* W2 = (float4*)d_ws;   // 20160 float4 = 322,560 B

    k_prep<<<79, 256, 0, stream>>>(tree_w, W2);
    fused_all<<<BATCH, 256, 0, stream>>>(x, conv_w, conv_b, W2, tree_b,
                                         fc_w, fc_b, out);
}